// Round 6
// baseline (236.556 us; speedup 1.0000x reference)
//
#include <hip/hip_runtime.h>
#include <math.h>

#define CIN   128
#define COUT  128
#define KKT   9
#define NSTAT 32768.0f   // B*H*W per-channel count

typedef __attribute__((ext_vector_type(8))) short bf16x8;
typedef __attribute__((ext_vector_type(4))) float f32x4;
typedef __attribute__((ext_vector_type(2))) float f32x2;

__device__ inline unsigned short f2bf(float f) {
    union { float f; unsigned u; } v; v.f = f;
    unsigned r = v.u + 0x7fffu + ((v.u >> 16) & 1u);
    return (unsigned short)(r >> 16);
}
// unpack bf16 c-pair dword -> float2 {even-ch, odd-ch}
__device__ inline f32x2 bf2(unsigned u) {
    union { unsigned u; float f; } lo, hi;
    lo.u = u << 16; hi.u = u & 0xffff0000u;
    f32x2 r; r[0] = lo.f; r[1] = hi.f; return r;
}

// publish LDS writes, then barrier — does NOT drain vmcnt (prefetch loads stay in flight)
#define PUB_BARRIER() do { asm volatile("s_waitcnt lgkmcnt(0)" ::: "memory"); \
                           __builtin_amdgcn_s_barrier(); } while (0)

// ---------------- ws layout (bytes) ----------------
// xt   @ 0         : 8388608   bf16 channel-last x[b][y][x][c] (dword c-pairs)
// tabg @ 8388608   : 7077888   [bh][9][64][6] dwords: {a01,a23, w00,w01, w10,w11}
// wb   @ 15466496  : 294912    [oc][kt*128+c] bf16
// wob  @ 15761408  : 73728     [32 ocpad][kt*128+c] bf16 (rows 18..31 zero)
// sums @ 15835136  : 512       sums|sumsq

// Fused: blocks 0..511 transpose x -> xt; blocks 512.. repack weights + zero stats
__global__ __launch_bounds__(512) void prep_all_k(const float* __restrict__ x,
                                                  unsigned* __restrict__ xt,
                                                  const float* __restrict__ w_def,
                                                  const float* __restrict__ w_off,
                                                  unsigned short* __restrict__ wb,
                                                  unsigned short* __restrict__ wob,
                                                  float* __restrict__ sums) {
    __shared__ float lt[128][65];
    const int bb = blockIdx.x;
    if (bb < 512) {
        const int b = bb >> 6, y = bb & 63;
        const int t = threadIdx.x, l = t & 63, g8 = t >> 6;   // g8: 0..7
        const float* xb = x + (b * 128) * 4096 + y * 64;
#pragma unroll
        for (int pass = 0; pass < 16; pass++) {
            int c = pass * 8 + g8;
            lt[c][l] = xb[c * 4096 + l];
        }
        __syncthreads();
        unsigned* xo = xt + (bb * 64) * 64;   // pixel base (dwords)
#pragma unroll
        for (int pass = 0; pass < 8; pass++) {
            int w = pass * 8 + g8;
            float f0 = lt[2 * l][w], f1 = lt[2 * l + 1][w];
            xo[w * 64 + l] = (unsigned)f2bf(f0) | ((unsigned)f2bf(f1) << 16);
        }
    } else {
        int i = (bb - 512) * 512 + threadIdx.x;
        if (i < 147456) {
            int oc = i / 1152, r = i - oc * 1152, kt = r >> 7, c = r & 127;
            wb[i] = f2bf(w_def[(oc * 128 + c) * 9 + kt]);
        } else if (i < 147456 + 36864) {
            int j = i - 147456;
            int ocp = j / 1152, r = j - ocp * 1152, kt = r >> 7, c = r & 127;
            wob[j] = (ocp < 18) ? f2bf(w_off[(ocp * 128 + c) * 9 + kt]) : (unsigned short)0;
        } else if (i < 147456 + 36864 + 256) {
            sums[i - 147456 - 36864] = 0.f;   // sums|sumsq zero (re-poisoned each launch)
        }
    }
}

// Offset conv + tap-table build. One block per (b,h). 512 thr = 8 waves.
// Writes packed tap table to GLOBAL so the GEMM kernel can use small blocks.
// LDS 55296: xrow[0,50688) + offl[50688,55296).
__global__ __launch_bounds__(512, 4) void offset_tab_k(const unsigned* __restrict__ xt,
                                                       const unsigned short* __restrict__ wob,
                                                       int* __restrict__ tabg) {
    __shared__ __align__(16) unsigned char smem[55296];
    unsigned short* xrow = (unsigned short*)smem;            // [3][66][128] bf16
    float* offl = (float*)(smem + 50688);                    // [18][64]

    const int t    = threadIdx.x;
    const int bh   = blockIdx.x;
    const int b    = bh >> 6;
    const int j_   = bh & 63;
    const int h    = ((j_ & 7) << 3) | (j_ >> 3);   // XCD-locality swizzle
    const int lane = t & 63;
    const int wv   = __builtin_amdgcn_readfirstlane(t >> 6);  // 0..7
    const int quad = lane >> 4, lo = lane & 15;
    const int l    = lane;
    const int g    = lane >> 2;

    const unsigned* xtb = xt + b * 262144;

    // ---- stage xrow: rows h-1..h+1, x = -1..64, zero-padded, swizzled ----
#pragma unroll
    for (int it = 0; it < 25; it++) {
        int p = wv + it * 8;
        if (p < 198) {
            int r = p / 66, xi = p - r * 66;
            int y = h + r - 1, x = xi - 1;
            unsigned u = 0;
            if ((unsigned)y < 64u && (unsigned)x < 64u) u = xtb[(y * 64 + x) * 64 + l];
            ((unsigned*)xrow)[(r * 66 + xi) * 64 + ((g ^ (xi & 15)) << 2) + (l & 3)] = u;
        }
    }
    __syncthreads();

    // ---- offset conv via MFMA: wave -> (mt = wv>>2, nt = wv&3), D[oc][w] ----
    {
        const int omt = wv >> 2, ont = wv & 3;
        f32x4 ao = {0.f, 0.f, 0.f, 0.f};
        const unsigned short* wrow = wob + (omt * 16 + lo) * 1152 + quad * 8;
        for (int kt = 0; kt < 9; kt++) {
            int ky = kt / 3, kx = kt - ky * 3;
            int xi = ont * 16 + lo + kx;
#pragma unroll
            for (int ch = 0; ch < 4; ch++) {
                int gg = ch * 4 + quad;
                bf16x8 af = *(const bf16x8*)(wrow + kt * 128 + ch * 32);
                bf16x8 bf = *(const bf16x8*)(xrow + (ky * 66 + xi) * 128 + ((gg ^ (xi & 15)) << 3));
                ao = __builtin_amdgcn_mfma_f32_16x16x32_bf16(af, bf, ao, 0, 0, 0);
            }
        }
#pragma unroll
        for (int r = 0; r < 4; r++) {
            int oc = omt * 16 + quad * 4 + r;
            if (oc < 18) offl[oc * 64 + ont * 16 + lo] = ao[r];
        }
    }
    __syncthreads();   // offl ready

    // ---- tap table -> global: packed corner pixel indices + combined weights ----
    int* tb = tabg + bh * 3456;
    for (int i = t; i < KKT * 64; i += 512) {
        int k = i >> 6, w2i = i & 63;
        float dy = offl[(2 * k) * 64 + w2i];
        float dx = offl[(2 * k + 1) * 64 + w2i];
        int ky = k / 3, kx = k - ky * 3;
        float ys = (float)(h - 1 + ky) + dy;
        float xs = (float)(w2i - 1 + kx) + dx;
        float y0f = floorf(ys), x0f = floorf(xs);
        float wyf = ys - y0f, wxf = xs - x0f;
        int iy0 = (int)y0f, ix0 = (int)x0f;
        int cy0 = min(max(iy0, 0), 63), cy1 = min(max(iy0 + 1, 0), 63);
        int px  = min(max(ix0, 0), 63), px2 = min(max(ix0 + 1, 0), 63);
        float wy0 = (iy0 >= 0 && iy0 < 64) ? (1.f - wyf) : 0.f;
        float wy1 = (iy0 + 1 >= 0 && iy0 + 1 < 64) ? wyf : 0.f;
        float wa  = (ix0 >= 0 && ix0 < 64) ? (1.f - wxf) : 0.f;
        float wbv = (ix0 + 1 >= 0 && ix0 + 1 < 64) ? wxf : 0.f;
        int a0 = cy0 * 64 + px, a1 = cy0 * 64 + px2;
        int a2 = cy1 * 64 + px, a3 = cy1 * 64 + px2;
        int base = k * 384 + w2i * 6;
        int2 ap; ap.x = a0 | (a1 << 16); ap.y = a2 | (a3 << 16);
        *(int2*)(tb + base) = ap;
        float2 wA; wA.x = wy0 * wa; wA.y = wy0 * wbv;
        float2 wB; wB.x = wy1 * wa; wB.y = wy1 * wbv;
        *(float2*)(tb + base + 2) = wA;
        *(float2*)(tb + base + 4) = wB;
    }
}

// Main GEMM: 1024 blocks (bh = bid&511, half = bid>>9 -> same XCD), 512 thr = 8 waves,
// 32 pixels per block. 4 blocks/CU (32 waves/CU) with INDEPENDENT 8-wave barriers
// and a full 128-VGPR budget — no spills, uncorrelated stalls.
// Per tap: wave gathers 4 px (lane = c-pair, coalesced), blends, writes samp dbuf,
// one barrier, then MFMA (wave = 16 oc x 2 px-tiles; A-frags from L2-hot wb).
// LDS 24320: tabl[0,6912) samp0[6912,15104) samp1[15104,23296).
__global__ __launch_bounds__(512, 4) void deform_gemm_k(const unsigned* __restrict__ xt,
                                                        const int* __restrict__ tabg,
                                                        const unsigned short* __restrict__ wb,
                                                        const float* __restrict__ b_def,
                                                        float* __restrict__ out,
                                                        float* __restrict__ sums,
                                                        float* __restrict__ sumsq) {
    __shared__ __align__(16) unsigned char smem[23296];
    int*            tabl  = (int*)smem;                      // [9][32][6] dwords
    unsigned short* samp0 = (unsigned short*)(smem + 6912);  // [32][128] bf16
    unsigned short* samp1 = (unsigned short*)(smem + 15104);

    const int t    = threadIdx.x;
    const int bid  = blockIdx.x;
    const int bh   = bid & 511;
    const int half = bid >> 9;                 // pixel half 0/1 (same XCD: +512 % 8 == 0)
    const int b    = bh >> 6;
    const int j_   = bh & 63;
    const int h    = ((j_ & 7) << 3) | (j_ >> 3);
    const int lane = t & 63;
    const int wv   = __builtin_amdgcn_readfirstlane(t >> 6);  // 0..7
    const int quad = lane >> 4, lo = lane & 15;
    const int l    = lane;        // c-pair index for gathers
    const int g    = lane >> 2;   // c-octet index 0..15

    const unsigned* xtb = xt + b * 262144;

    // ---- load this block's tap-table slice (9 taps x 32 px x 6 dwords) ----
    const int* tg = tabg + bh * 3456 + half * 192;
    for (int i = t; i < 1728; i += 512) {
        int kt = i / 192, j = i - kt * 192;
        tabl[kt * 192 + j] = tg[kt * 384 + j];
    }
    __syncthreads();

    const int p0 = wv * 4;    // this wave's 4 local pixels
    f32x4 acc[2];
#pragma unroll
    for (int n = 0; n < 2; n++)
#pragma unroll
        for (int r = 0; r < 4; r++) acc[n][r] = 0.f;

    const unsigned short* abase = wb + (wv * 16 + lo) * 1152 + quad * 8;
    unsigned u0[4], u1[4], u2[4], u3[4];

    // gather tap k's 4 corners for this wave's 4 pixels (coalesced: lane = c-pair)
#define GATHER(k_)                                                        \
    do {                                                                  \
        _Pragma("unroll")                                                 \
        for (int i = 0; i < 4; i++) {                                     \
            int p = p0 + i;                                               \
            int2 ap = *(const int2*)&tabl[(k_) * 192 + p * 6];            \
            unsigned a0 = (unsigned)ap.x & 0xffffu, a1 = (unsigned)ap.x >> 16; \
            unsigned a2 = (unsigned)ap.y & 0xffffu, a3 = (unsigned)ap.y >> 16; \
            u0[i] = xtb[(a0 << 6) + l]; u1[i] = xtb[(a1 << 6) + l];       \
            u2[i] = xtb[(a2 << 6) + l]; u3[i] = xtb[(a3 << 6) + l];       \
        }                                                                 \
    } while (0)

    GATHER(0);

    for (int kt = 0; kt < KKT; kt++) {
        // blend staged regs -> samp[kt&1] (swizzled, conflict-free)
        unsigned* sb = (unsigned*)((kt & 1) ? samp1 : samp0);
#pragma unroll
        for (int i = 0; i < 4; i++) {
            int p = p0 + i;
            float2 wA = *(const float2*)&tabl[kt * 192 + p * 6 + 2];
            float2 wB = *(const float2*)&tabl[kt * 192 + p * 6 + 4];
            f32x2 s = bf2(u0[i]) * wA.x;
            s += bf2(u1[i]) * wA.y;
            s += bf2(u2[i]) * wB.x;
            s += bf2(u3[i]) * wB.y;
            unsigned pk;
            asm("v_cvt_pk_bf16_f32 %0, %1, %2" : "=v"(pk) : "v"(s[0]), "v"(s[1]));
            sb[p * 64 + ((g ^ (p & 15)) << 2) + (l & 3)] = pk;
        }
        // prefetch next tap's gathers: stay in flight across barrier + MFMA
        if (kt < KKT - 1) GATHER(kt + 1);
        PUB_BARRIER();
        const unsigned short* sbs = (kt & 1) ? samp1 : samp0;
        bf16x8 af[4];
#pragma unroll
        for (int ch = 0; ch < 4; ch++)
            af[ch] = *(const bf16x8*)(abase + kt * 128 + ch * 32);
#pragma unroll
        for (int ch = 0; ch < 4; ch++) {
            int gg = ch * 4 + quad;
#pragma unroll
            for (int n = 0; n < 2; n++) {
                bf16x8 bfv = *(const bf16x8*)(sbs + (n * 16 + lo) * 128 + ((gg ^ lo) << 3));
                acc[n] = __builtin_amdgcn_mfma_f32_16x16x32_bf16(af[ch], bfv, acc[n], 0, 0, 0);
            }
        }
    }
#undef GATHER

    // ---- epilogue: bias + store + fused BN stats (direct global atomics) ----
    float* ob = out + b * COUT * 4096 + h * 64 + half * 32;
#pragma unroll
    for (int r = 0; r < 4; r++) {
        int oc = wv * 16 + quad * 4 + r;
        float bia = b_def[oc];
        float ssum = 0.f, qsum = 0.f;
#pragma unroll
        for (int n = 0; n < 2; n++) {
            float v = acc[n][r] + bia;
            ob[oc * 4096 + n * 16 + lo] = v;
            ssum += v; qsum += v * v;
        }
#pragma unroll
        for (int d = 1; d < 16; d <<= 1) {
            ssum += __shfl_xor(ssum, d, 64);
            qsum += __shfl_xor(qsum, d, 64);
        }
        if (lo == 0) {
            atomicAdd(&sums[oc], ssum);
            atomicAdd(&sumsq[oc], qsum);
        }
    }
}

__global__ __launch_bounds__(256) void bn_silu_k(float* __restrict__ out,
                                                 const float* __restrict__ sums,
                                                 const float* __restrict__ sumsq,
                                                 const float* __restrict__ gamma,
                                                 const float* __restrict__ beta) {
    __shared__ float sc_s[128], sh_s[128];
    int t = threadIdx.x;
    if (t < 128) {
        const float invN = 1.f / NSTAT;
        float m = sums[t] * invN;
        float v = fmaf(-m, m, sumsq[t] * invN);
        float sc = gamma[t] * rsqrtf(v + 1e-5f);
        sc_s[t] = sc;
        sh_s[t] = beta[t] - m * sc;
    }
    __syncthreads();
    int i = blockIdx.x * 256 + t;
    float4 v = ((float4*)out)[i];
    int oc = (i >> 10) & 127;
    float sc = sc_s[oc], sh = sh_s[oc];
    float z0 = v.x * sc + sh;
    float z1 = v.y * sc + sh;
    float z2 = v.z * sc + sh;
    float z3 = v.w * sc + sh;
    v.x = z0 / (1.f + __expf(-z0));
    v.y = z1 / (1.f + __expf(-z1));
    v.z = z2 / (1.f + __expf(-z2));
    v.w = z3 / (1.f + __expf(-z3));
    ((float4*)out)[i] = v;
}

extern "C" void kernel_launch(void* const* d_in, const int* in_sizes, int n_in,
                              void* d_out, int out_size, void* d_ws, size_t ws_size,
                              hipStream_t stream) {
    const float* x     = (const float*)d_in[0];
    const float* w_off = (const float*)d_in[1];
    const float* w_def = (const float*)d_in[2];
    const float* b_def = (const float*)d_in[3];
    const float* gamma = (const float*)d_in[4];
    const float* beta  = (const float*)d_in[5];
    float* out = (float*)d_out;

    unsigned*       xt   = (unsigned*)d_ws;                               // 8388608 B
    int*            tabg = (int*)((char*)d_ws + 8388608);                 // 7077888 B
    unsigned short* wb   = (unsigned short*)((char*)d_ws + 15466496);     // 294912 B
    unsigned short* wob  = (unsigned short*)((char*)d_ws + 15761408);     // 73728 B
    float*          sums = (float*)((char*)d_ws + 15835136);              // 128
    float*          sumsq = sums + 128;

    prep_all_k<<<873, 512, 0, stream>>>(x, xt, w_def, w_off, wb, wob, sums);
    offset_tab_k<<<512, 512, 0, stream>>>(xt, wob, tabg);
    deform_gemm_k<<<1024, 512, 0, stream>>>(xt, tabg, wb, b_def, out, sums, sumsq);
    bn_silu_k<<<4096, 256, 0, stream>>>(out, sums, sumsq, gamma, beta);
}

// Round 7
// 163.199 us; speedup vs baseline: 1.4495x; 1.4495x over previous
//
#include <hip/hip_runtime.h>
#include <math.h>

#define CIN   128
#define COUT  128
#define KKT   9
#define NSTAT 32768.0f   // B*H*W per-channel count

typedef __attribute__((ext_vector_type(8))) short bf16x8;
typedef __attribute__((ext_vector_type(4))) float f32x4;
typedef __attribute__((ext_vector_type(2))) float f32x2;

__device__ inline unsigned short f2bf(float f) {
    union { float f; unsigned u; } v; v.f = f;
    unsigned r = v.u + 0x7fffu + ((v.u >> 16) & 1u);
    return (unsigned short)(r >> 16);
}
// unpack bf16 c-pair dword -> float2 {even-ch, odd-ch}
__device__ inline f32x2 bf2(unsigned u) {
    union { unsigned u; float f; } lo, hi;
    lo.u = u << 16; hi.u = u & 0xffff0000u;
    f32x2 r; r[0] = lo.f; r[1] = hi.f; return r;
}
// bilinear blend of one c-pair dword from 4 corners -> packed bf16 pair
__device__ inline unsigned blend1(unsigned c00, unsigned c01, unsigned c10, unsigned c11,
                                  float w00, float w01, float w10, float w11) {
    f32x2 s = bf2(c00) * w00;
    s += bf2(c01) * w01;
    s += bf2(c10) * w10;
    s += bf2(c11) * w11;
    unsigned pk;
    asm("v_cvt_pk_bf16_f32 %0, %1, %2" : "=v"(pk) : "v"(s[0]), "v"(s[1]));
    return pk;
}

// publish LDS writes, then barrier — does NOT drain vmcnt (prefetch loads stay in flight)
#define PUB_BARRIER() do { asm volatile("s_waitcnt lgkmcnt(0)" ::: "memory"); \
                           __builtin_amdgcn_s_barrier(); } while (0)

// ---------------- ws layout (bytes) ----------------
// xt   @ 0        : 8388608  bf16 channel-last x[b][y][x][c] (dword c-pairs)
// wb   @ 8388608  : 294912   [oc][kt*128+c] bf16
// wob  @ 8683520  : 73728    [32 ocpad][kt*128+c] bf16 (rows 18..31 zero)
// sums @ 8757248  : 512      sums|sumsq

// Fused: blocks 0..511 transpose x -> xt; blocks 512.. repack weights + zero stats
__global__ __launch_bounds__(512) void prep_all_k(const float* __restrict__ x,
                                                  unsigned* __restrict__ xt,
                                                  const float* __restrict__ w_def,
                                                  const float* __restrict__ w_off,
                                                  unsigned short* __restrict__ wb,
                                                  unsigned short* __restrict__ wob,
                                                  float* __restrict__ sums) {
    __shared__ float lt[128][65];
    const int bb = blockIdx.x;
    if (bb < 512) {
        const int b = bb >> 6, y = bb & 63;
        const int t = threadIdx.x, l = t & 63, g8 = t >> 6;   // g8: 0..7
        const float* xb = x + (b * 128) * 4096 + y * 64;
#pragma unroll
        for (int pass = 0; pass < 16; pass++) {
            int c = pass * 8 + g8;
            lt[c][l] = xb[c * 4096 + l];
        }
        __syncthreads();
        unsigned* xo = xt + (bb * 64) * 64;   // pixel base (dwords)
#pragma unroll
        for (int pass = 0; pass < 8; pass++) {
            int w = pass * 8 + g8;
            float f0 = lt[2 * l][w], f1 = lt[2 * l + 1][w];
            xo[w * 64 + l] = (unsigned)f2bf(f0) | ((unsigned)f2bf(f1) << 16);
        }
    } else {
        int i = (bb - 512) * 512 + threadIdx.x;
        if (i < 147456) {
            int oc = i / 1152, r = i - oc * 1152, kt = r >> 7, c = r & 127;
            wb[i] = f2bf(w_def[(oc * 128 + c) * 9 + kt]);
        } else if (i < 147456 + 36864) {
            int j = i - 147456;
            int ocp = j / 1152, r = j - ocp * 1152, kt = r >> 7, c = r & 127;
            wob[j] = (ocp < 18) ? f2bf(w_off[(ocp * 128 + c) * 9 + kt]) : (unsigned short)0;
        } else if (i < 147456 + 36864 + 256) {
            sums[i - 147456 - 36864] = 0.f;   // sums|sumsq zero (re-poisoned each launch)
        }
    }
}

// One block per (b,h). 1024 thr = 16 waves, 1 block/CU (LDS ~144 KB).
// Stages a 5-row x 68-col window of x in LDS; bilinear gathers come from LDS
// (ds_read_b128, XOR-swizzled by row) instead of scattered L2 reads — ~7x less
// data motion. Block-uniform fallback to global gathers if any tap's corners
// fall outside the window (|offset| >= 1 somewhere).
// LDS map: x5[0,87040) samp0[87040,103424) samp1[103424,119808)
//          tab[119808,138240) offl[138240,142848) stat[142848,143872)
__global__ __launch_bounds__(1024, 4) void deform_main_k(const unsigned* __restrict__ xt,
                                                         const unsigned short* __restrict__ wb,
                                                         const unsigned short* __restrict__ wob,
                                                         const float* __restrict__ b_def,
                                                         float* __restrict__ out,
                                                         float* __restrict__ sums,
                                                         float* __restrict__ sumsq) {
    __shared__ __align__(16) unsigned char smem[143872];
    __shared__ int s_bad;
    unsigned*       x5dw  = (unsigned*)smem;                    // [340][64] dwords, swizzled
    unsigned short* samp0 = (unsigned short*)(smem + 87040);    // [64][128] bf16
    unsigned short* samp1 = (unsigned short*)(smem + 103424);
    int*            tabl  = (int*)(smem + 119808);              // [9*64][8] dwords
    float*          offl  = (float*)(smem + 138240);            // [18][64]
    float*          stat  = (float*)(smem + 142848);            // [256]

    const int t    = threadIdx.x;
    const int bh   = blockIdx.x;
    const int b    = bh >> 6;
    const int j_   = bh & 63;
    const int h    = ((j_ & 7) << 3) | (j_ >> 3);   // XCD-locality swizzle
    const int lane = t & 63;
    const int wv   = __builtin_amdgcn_readfirstlane(t >> 6);  // 0..15
    const int quad = lane >> 4, lo = lane & 15;
    const int l    = lane;        // c-pair index (staging / global gathers)
    const int sp   = lane >> 4;   // sub-pixel 0..3 (LDS-gather path)
    const int ci   = lane & 15;   // c-octet 0..15  (LDS-gather path)

    if (t < 256) stat[t] = 0.f;
    if (t == 0) s_bad = 0;

    const unsigned* xtb = xt + b * 262144;   // dwords per batch image

    // ---- stage 5-row window: rows h-2..h+2, cols -2..65, zero-padded, swizzled ----
    // swizzle contract: dword for (window-row k, c-pair cpr) at k*64 + (cpr ^ ((k&7)<<2))
    for (int it = 0; it < 22; it++) {
        int k = wv + it * 16;
        if (k < 340) {
            int rr = k / 68, xi = k - rr * 68;   // scalar math (k wave-uniform)
            int y = h + rr - 2, x = xi - 2;
            unsigned u = 0;
            if ((unsigned)y < 64u && (unsigned)x < 64u) u = xtb[(y * 64 + x) * 64 + l];
            x5dw[k * 64 + (l ^ ((k & 7) << 2))] = u;
        }
    }
    __syncthreads();

    // ---- offset conv via MFMA (waves 0..7), B from the staged window ----
    {
        const int omt = wv >> 2, ont = wv & 3;
        if (wv < 8) {
            f32x4 ao = {0.f, 0.f, 0.f, 0.f};
            const unsigned short* wrow = wob + (omt * 16 + lo) * 1152 + quad * 8;
            for (int kt = 0; kt < 9; kt++) {
                int ky = kt / 3, kx = kt - ky * 3;
                int k5 = (ky + 1) * 68 + (ont * 16 + lo + kx + 1);   // window row idx
#pragma unroll
                for (int ch = 0; ch < 4; ch++) {
                    int gg = ch * 4 + quad;
                    bf16x8 af = *(const bf16x8*)(wrow + kt * 128 + ch * 32);
                    bf16x8 bfv = *(const bf16x8*)((const unsigned short*)
                                      &x5dw[k5 * 64 + ((gg ^ (k5 & 7)) << 2)]);
                    ao = __builtin_amdgcn_mfma_f32_16x16x32_bf16(af, bfv, ao, 0, 0, 0);
                }
            }
#pragma unroll
            for (int r = 0; r < 4; r++) {
                int oc = omt * 16 + quad * 4 + r;
                if (oc < 18) offl[oc * 64 + ont * 16 + lo] = ao[r];
            }
        }
    }
    __syncthreads();   // offl ready

    // ---- tap tables: window row-idx (or -1) + clamped global addrs + weights ----
    int localbad = 0;
    for (int i = t; i < KKT * 64; i += 1024) {
        int k = i >> 6, w2i = i & 63;
        float dy = offl[(2 * k) * 64 + w2i];
        float dx = offl[(2 * k + 1) * 64 + w2i];
        int ky = k / 3, kx = k - ky * 3;
        float ys = (float)(h - 1 + ky) + dy;
        float xs = (float)(w2i - 1 + kx) + dx;
        float y0f = floorf(ys), x0f = floorf(xs);
        float wyf = ys - y0f, wxf = xs - x0f;
        int iy0 = (int)y0f, ix0 = (int)x0f;
        int cy0 = min(max(iy0, 0), 63), cy1 = min(max(iy0 + 1, 0), 63);
        int px  = min(max(ix0, 0), 63), px2 = min(max(ix0 + 1, 0), 63);
        float wy0 = (iy0 >= 0 && iy0 < 64) ? (1.f - wyf) : 0.f;
        float wy1 = (iy0 + 1 >= 0 && iy0 + 1 < 64) ? wyf : 0.f;
        float wa  = (ix0 >= 0 && ix0 < 64) ? (1.f - wxf) : 0.f;
        float wbv = (ix0 + 1 >= 0 && ix0 + 1 < 64) ? wxf : 0.f;
        int wr = iy0 - (h - 2), wc = ix0 + 2;
        int inw = ((unsigned)wr <= 3u) && ((unsigned)wc <= 66u);
        if (!inw) localbad = 1;
        int base = i * 8;
        tabl[base + 0] = inw ? (wr * 68 + wc) : 0;
        tabl[base + 1] = (cy0 * 64 + px) | ((cy0 * 64 + px2) << 16);
        tabl[base + 2] = (cy1 * 64 + px) | ((cy1 * 64 + px2) << 16);
        ((float*)tabl)[base + 4] = wy0 * wa;   // w00
        ((float*)tabl)[base + 5] = wy0 * wbv;  // w01
        ((float*)tabl)[base + 6] = wy1 * wa;   // w10
        ((float*)tabl)[base + 7] = wy1 * wbv;  // w11
    }
    if (localbad) atomicOr(&s_bad, 1);
    __syncthreads();
    const int bad = s_bad;   // block-uniform

    // ---- main tap loop ----
    // wave -> (ot = wv&7 oc-tile, ph = wv>>3 px half); produce own 4 px (p0 = wv*4)
    const int ot = wv & 7, ph = wv >> 3;
    const int p0 = wv * 4;
    f32x4 acc[2];
#pragma unroll
    for (int jj = 0; jj < 2; jj++)
#pragma unroll
        for (int r = 0; r < 4; r++) acc[jj][r] = 0.f;

    const unsigned short* abase = wb + (ot * 16 + lo) * 1152 + quad * 8;
    bf16x8 afc[4], afn[4];
#pragma unroll
    for (int ch = 0; ch < 4; ch++) afc[ch] = *(const bf16x8*)(abase + ch * 32);

    if (!bad) {
        // LDS-gather path: lane = (sub-px sp, c-octet ci); one b128 per corner
        const uint4* x5q = (const uint4*)x5dw;
        for (int kt = 0; kt < KKT; kt++) {
            int p = p0 + sp;
            int tb = (kt * 64 + p) * 8;
            int k00 = tabl[tb];
            float4 w = *(const float4*)&tabl[tb + 4];
            int k01 = k00 + 1, k10 = k00 + 68, k11 = k00 + 69;
            uint4 c00 = x5q[k00 * 16 + (ci ^ (k00 & 7))];
            uint4 c01 = x5q[k01 * 16 + (ci ^ (k01 & 7))];
            uint4 c10 = x5q[k10 * 16 + (ci ^ (k10 & 7))];
            uint4 c11 = x5q[k11 * 16 + (ci ^ (k11 & 7))];
            uint4 bq;
            bq.x = blend1(c00.x, c01.x, c10.x, c11.x, w.x, w.y, w.z, w.w);
            bq.y = blend1(c00.y, c01.y, c10.y, c11.y, w.x, w.y, w.z, w.w);
            bq.z = blend1(c00.z, c01.z, c10.z, c11.z, w.x, w.y, w.z, w.w);
            bq.w = blend1(c00.w, c01.w, c10.w, c11.w, w.x, w.y, w.z, w.w);
            unsigned* sb = (unsigned*)((kt & 1) ? samp1 : samp0);
            *(uint4*)&sb[p * 64 + ((ci ^ (p & 15)) << 2)] = bq;
            // A-frag prefetch for next tap (stays in flight across barrier+MFMA)
            int ktn = (kt < KKT - 1) ? kt + 1 : kt;
#pragma unroll
            for (int ch = 0; ch < 4; ch++)
                afn[ch] = *(const bf16x8*)(abase + ktn * 128 + ch * 32);
            PUB_BARRIER();
            const unsigned short* sbs = (kt & 1) ? samp1 : samp0;
#pragma unroll
            for (int ch = 0; ch < 4; ch++) {
                int gg = ch * 4 + quad;
#pragma unroll
                for (int jj = 0; jj < 2; jj++) {
                    int n = 2 * ph + jj;
                    bf16x8 bfv = *(const bf16x8*)(sbs + (n * 16 + lo) * 128 + ((gg ^ lo) << 3));
                    acc[jj] = __builtin_amdgcn_mfma_f32_16x16x32_bf16(afc[ch], bfv, acc[jj], 0, 0, 0);
                }
            }
#pragma unroll
            for (int ch = 0; ch < 4; ch++) afc[ch] = afn[ch];
        }
    } else {
        // global fallback (R6-proven): lane = c-pair, 4 px per wave, prefetched gathers
        unsigned u0[4], u1[4], u2[4], u3[4];
#define GATHERG(k_)                                                          \
        do {                                                                 \
            _Pragma("unroll")                                                \
            for (int i = 0; i < 4; i++) {                                    \
                int p = p0 + i;                                              \
                int bse = ((k_) * 64 + p) * 8;                               \
                unsigned a01 = (unsigned)tabl[bse + 1];                      \
                unsigned a23 = (unsigned)tabl[bse + 2];                      \
                u0[i] = xtb[((a01 & 0xffffu) << 6) + l];                     \
                u1[i] = xtb[((a01 >> 16) << 6) + l];                         \
                u2[i] = xtb[((a23 & 0xffffu) << 6) + l];                     \
                u3[i] = xtb[((a23 >> 16) << 6) + l];                         \
            }                                                                \
        } while (0)
        GATHERG(0);
        for (int kt = 0; kt < KKT; kt++) {
            unsigned* sb = (unsigned*)((kt & 1) ? samp1 : samp0);
#pragma unroll
            for (int i = 0; i < 4; i++) {
                int p = p0 + i;
                float4 w = *(const float4*)&tabl[(kt * 64 + p) * 8 + 4];
                f32x2 s = bf2(u0[i]) * w.x;
                s += bf2(u1[i]) * w.y;
                s += bf2(u2[i]) * w.z;
                s += bf2(u3[i]) * w.w;
                unsigned pk;
                asm("v_cvt_pk_bf16_f32 %0, %1, %2" : "=v"(pk) : "v"(s[0]), "v"(s[1]));
                sb[p * 64 + (((l >> 2) ^ (p & 15)) << 2) + (l & 3)] = pk;
            }
            if (kt < KKT - 1) GATHERG(kt + 1);
            int ktn = (kt < KKT - 1) ? kt + 1 : kt;
#pragma unroll
            for (int ch = 0; ch < 4; ch++)
                afn[ch] = *(const bf16x8*)(abase + ktn * 128 + ch * 32);
            PUB_BARRIER();
            const unsigned short* sbs = (kt & 1) ? samp1 : samp0;
#pragma unroll
            for (int ch = 0; ch < 4; ch++) {
                int gg = ch * 4 + quad;
#pragma unroll
                for (int jj = 0; jj < 2; jj++) {
                    int n = 2 * ph + jj;
                    bf16x8 bfv = *(const bf16x8*)(sbs + (n * 16 + lo) * 128 + ((gg ^ lo) << 3));
                    acc[jj] = __builtin_amdgcn_mfma_f32_16x16x32_bf16(afc[ch], bfv, acc[jj], 0, 0, 0);
                }
            }
#pragma unroll
            for (int ch = 0; ch < 4; ch++) afc[ch] = afn[ch];
        }
#undef GATHERG
    }

    // ---- epilogue: bias + store + fused BN stats ----
    float* ob = out + b * COUT * 4096 + h * 64;
#pragma unroll
    for (int r = 0; r < 4; r++) {
        int oc = ot * 16 + quad * 4 + r;
        float bia = b_def[oc];
        float ssum = 0.f, qsum = 0.f;
#pragma unroll
        for (int jj = 0; jj < 2; jj++) {
            int n = 2 * ph + jj;
            float v = acc[jj][r] + bia;
            ob[oc * 4096 + n * 16 + lo] = v;
            ssum += v; qsum += v * v;
        }
#pragma unroll
        for (int d = 1; d < 16; d <<= 1) {
            ssum += __shfl_xor(ssum, d, 64);
            qsum += __shfl_xor(qsum, d, 64);
        }
        if (lo == 0) { atomicAdd(&stat[oc], ssum); atomicAdd(&stat[128 + oc], qsum); }
    }
    __syncthreads();
    if (t < 256) {
        float* gp = (t < 128) ? (sums + t) : (sumsq + (t - 128));
        atomicAdd(gp, stat[t]);
    }
}

__global__ __launch_bounds__(256) void bn_silu_k(float* __restrict__ out,
                                                 const float* __restrict__ sums,
                                                 const float* __restrict__ sumsq,
                                                 const float* __restrict__ gamma,
                                                 const float* __restrict__ beta) {
    __shared__ float sc_s[128], sh_s[128];
    int t = threadIdx.x;
    if (t < 128) {
        const float invN = 1.f / NSTAT;
        float m = sums[t] * invN;
        float v = fmaf(-m, m, sumsq[t] * invN);
        float sc = gamma[t] * rsqrtf(v + 1e-5f);
        sc_s[t] = sc;
        sh_s[t] = beta[t] - m * sc;
    }
    __syncthreads();
    int i = blockIdx.x * 256 + t;
    float4 v = ((float4*)out)[i];
    int oc = (i >> 10) & 127;
    float sc = sc_s[oc], sh = sh_s[oc];
    float z0 = v.x * sc + sh;
    float z1 = v.y * sc + sh;
    float z2 = v.z * sc + sh;
    float z3 = v.w * sc + sh;
    v.x = z0 / (1.f + __expf(-z0));
    v.y = z1 / (1.f + __expf(-z1));
    v.z = z2 / (1.f + __expf(-z2));
    v.w = z3 / (1.f + __expf(-z3));
    ((float4*)out)[i] = v;
}

extern "C" void kernel_launch(void* const* d_in, const int* in_sizes, int n_in,
                              void* d_out, int out_size, void* d_ws, size_t ws_size,
                              hipStream_t stream) {
    const float* x     = (const float*)d_in[0];
    const float* w_off = (const float*)d_in[1];
    const float* w_def = (const float*)d_in[2];
    const float* b_def = (const float*)d_in[3];
    const float* gamma = (const float*)d_in[4];
    const float* beta  = (const float*)d_in[5];
    float* out = (float*)d_out;

    unsigned*       xt   = (unsigned*)d_ws;                               // 8388608 B
    unsigned short* wb   = (unsigned short*)((char*)d_ws + 8388608);      // 294912 B
    unsigned short* wob  = (unsigned short*)((char*)d_ws + 8683520);      // 73728 B
    float*          sums = (float*)((char*)d_ws + 8757248);               // 128
    float*          sumsq = sums + 128;

    prep_all_k<<<873, 512, 0, stream>>>(x, xt, w_def, w_off, wb, wob, sums);
    deform_main_k<<<512, 1024, 0, stream>>>(xt, wb, wob, b_def, out, sums, sumsq);
    bn_silu_k<<<4096, 256, 0, stream>>>(out, sums, sumsq, gamma, beta);
}

// Round 8
// 160.011 us; speedup vs baseline: 1.4784x; 1.0199x over previous
//
#include <hip/hip_runtime.h>
#include <math.h>

#define CIN   128
#define COUT  128
#define KKT   9
#define NSTAT 32768.0f   // B*H*W per-channel count

typedef __attribute__((ext_vector_type(8))) short bf16x8;
typedef __attribute__((ext_vector_type(4))) float f32x4;
typedef __attribute__((ext_vector_type(2))) float f32x2;

__device__ inline unsigned short f2bf(float f) {
    union { float f; unsigned u; } v; v.f = f;
    unsigned r = v.u + 0x7fffu + ((v.u >> 16) & 1u);
    return (unsigned short)(r >> 16);
}
// unpack bf16 c-pair dword -> float2 {even-ch, odd-ch}
__device__ inline f32x2 bf2(unsigned u) {
    union { unsigned u; float f; } lo, hi;
    lo.u = u << 16; hi.u = u & 0xffff0000u;
    f32x2 r; r[0] = lo.f; r[1] = hi.f; return r;
}

// publish LDS writes, then barrier — does NOT drain vmcnt (prefetch loads stay in flight)
#define PUB_BARRIER() do { asm volatile("s_waitcnt lgkmcnt(0)" ::: "memory"); \
                           __builtin_amdgcn_s_barrier(); } while (0)

// ---------------- ws layout (bytes) ----------------
// xt  : 16777216   bf16 channel-last x[b][y][x][c], stored as dword c-pairs
// wb  : 294912     [oc][kt*128+c] bf16   (main conv A)
// wob : 73728      [32 ocpad][kt*128+c] bf16 (offset conv A, rows 18..31 zero)
// sums: 512 | sumsq

// Fused: blocks 0..511 transpose x -> xt; blocks 512.. repack weights + zero stats
__global__ __launch_bounds__(512) void prep_all_k(const float* __restrict__ x,
                                                  unsigned* __restrict__ xt,
                                                  const float* __restrict__ w_def,
                                                  const float* __restrict__ w_off,
                                                  unsigned short* __restrict__ wb,
                                                  unsigned short* __restrict__ wob,
                                                  float* __restrict__ sums) {
    __shared__ float lt[128][65];
    const int bb = blockIdx.x;
    if (bb < 512) {
        const int b = bb >> 6, y = bb & 63;
        const int t = threadIdx.x, l = t & 63, g8 = t >> 6;   // g8: 0..7
        const float* xb = x + (b * 128) * 4096 + y * 64;
#pragma unroll
        for (int pass = 0; pass < 16; pass++) {
            int c = pass * 8 + g8;
            lt[c][l] = xb[c * 4096 + l];
        }
        __syncthreads();
        unsigned* xo = xt + (bb * 64) * 64;   // pixel base (dwords)
#pragma unroll
        for (int pass = 0; pass < 8; pass++) {
            int w = pass * 8 + g8;
            float f0 = lt[2 * l][w], f1 = lt[2 * l + 1][w];
            xo[w * 64 + l] = (unsigned)f2bf(f0) | ((unsigned)f2bf(f1) << 16);
        }
    } else {
        int i = (bb - 512) * 512 + threadIdx.x;
        if (i < 147456) {
            int oc = i / 1152, r = i - oc * 1152, kt = r >> 7, c = r & 127;
            wb[i] = f2bf(w_def[(oc * 128 + c) * 9 + kt]);
        } else if (i < 147456 + 36864) {
            int j = i - 147456;
            int ocp = j / 1152, r = j - ocp * 1152, kt = r >> 7, c = r & 127;
            wob[j] = (ocp < 18) ? f2bf(w_off[(ocp * 128 + c) * 9 + kt]) : (unsigned short)0;
        } else if (i < 147456 + 36864 + 256) {
            sums[i - 147456 - 36864] = 0.f;   // sums|sumsq zero (re-poisoned each launch)
        }
    }
}

// One block per (b,h). 1024 threads = 16 waves -> 32 waves/CU resident.
// XCD-BATCH AFFINITY: blockIdx -> XCD is round-robin (bid % 8), so b = bid & 7
// pins each XCD to ONE batch image: its xt working set (1 MB) + wb (0.3 MB)
// fit the 4 MB private L2 -> all bilinear gathers are L2 hits, no L3 latency.
// LDS 52224 B: xrow[0,50688) aliases {tab[0,18432) | samp0[18432,34816) |
// samp1[34816,51200) (offl[34816,39424) aliased, dead before tap 1)}; stat[51200,52224).
__global__ __launch_bounds__(1024, 8) void deform_main_k(const unsigned* __restrict__ xt,
                                                         const unsigned short* __restrict__ wb,
                                                         const unsigned short* __restrict__ wob,
                                                         const float* __restrict__ b_def,
                                                         float* __restrict__ out,
                                                         float* __restrict__ sums,
                                                         float* __restrict__ sumsq) {
    __shared__ __align__(16) unsigned char smem[52224];
    unsigned short* xrow  = (unsigned short*)smem;             // [3][66][128] bf16, 50688 B
    int*            tab   = (int*)smem;                        // [9*64][8] dwords, 18432 B
    unsigned short* samp0 = (unsigned short*)(smem + 18432);   // [64][128] bf16
    unsigned short* samp1 = (unsigned short*)(smem + 34816);
    float* offl = (float*)(smem + 34816);                      // [18][64] — aliases samp1
    float* stat = (float*)(smem + 51200);                      // [256]

    const int t    = threadIdx.x;
    const int bh   = blockIdx.x;
    const int b    = bh & 7;        // XCD = bid % 8 -> one batch image per XCD
    const int h    = bh >> 3;       // row 0..63
    const int lane = t & 63;
    const int wv   = __builtin_amdgcn_readfirstlane(t >> 6);  // 0..15
    const int quad = lane >> 4, lo = lane & 15;
    const int l    = lane;        // c-pair index for gathers
    const int g    = lane >> 2;   // c-octet index 0..15

    const unsigned* xtb = xt + b * 262144;   // dwords per batch image

    // ---- stage xrow: rows h-1..h+1, x = -1..64, zero-padded, swizzled ----
#pragma unroll
    for (int it = 0; it < 13; it++) {
        int p = wv + it * 16;
        if (p < 198) {
            int r = p / 66, xi = p - r * 66;
            int y = h + r - 1, x = xi - 1;
            unsigned u = 0;
            if ((unsigned)y < 64u && (unsigned)x < 64u) u = xtb[(y * 64 + x) * 64 + l];
            ((unsigned*)xrow)[(r * 66 + xi) * 64 + ((g ^ (xi & 15)) << 2) + (l & 3)] = u;
        }
    }
    __syncthreads();

    // ---- offset conv via MFMA (waves 0..7): wave -> (mt = wv>>2, nt = wv&3) ----
    const int omt = wv >> 2, ont = wv & 3;
    f32x4 ao = {0.f, 0.f, 0.f, 0.f};
    if (wv < 8) {
        const unsigned short* wrow = wob + (omt * 16 + lo) * 1152 + quad * 8;
        for (int kt = 0; kt < 9; kt++) {
            int ky = kt / 3, kx = kt - ky * 3;
            int xi = ont * 16 + lo + kx;   // xrow x-index = w + kx
#pragma unroll
            for (int ch = 0; ch < 4; ch++) {
                int gg = ch * 4 + quad;
                bf16x8 af = *(const bf16x8*)(wrow + kt * 128 + ch * 32);
                bf16x8 bf = *(const bf16x8*)(xrow + (ky * 66 + xi) * 128 + ((gg ^ (xi & 15)) << 3));
                ao = __builtin_amdgcn_mfma_f32_16x16x32_bf16(af, bf, ao, 0, 0, 0);
            }
        }
    }
    __syncthreads();   // all waves done reading xrow
    if (wv < 8) {
#pragma unroll
        for (int r = 0; r < 4; r++) {
            int oc = omt * 16 + quad * 4 + r;
            if (oc < 18) offl[oc * 64 + ont * 16 + lo] = ao[r];
        }
    }
    __syncthreads();   // offl ready; xrow region free for tab

    // ---- tap tables: 4 pixel addresses (dword idx) + 4 COMBINED weights per (tap,w) ----
    for (int i = t; i < KKT * 64; i += 1024) {
        int k = i >> 6, w2 = i & 63;
        float dy = offl[(2 * k) * 64 + w2];
        float dx = offl[(2 * k + 1) * 64 + w2];
        int ky = k / 3, kx = k - ky * 3;
        float ys = (float)(h - 1 + ky) + dy;
        float xs = (float)(w2 - 1 + kx) + dx;
        float y0f = floorf(ys), x0f = floorf(xs);
        float wyf = ys - y0f, wxf = xs - x0f;
        int iy0 = (int)y0f, ix0 = (int)x0f;
        int cy0 = min(max(iy0, 0), 63), cy1 = min(max(iy0 + 1, 0), 63);
        int px  = min(max(ix0, 0), 63), px2 = min(max(ix0 + 1, 0), 63);
        float wy0 = (iy0 >= 0 && iy0 < 64) ? (1.f - wyf) : 0.f;
        float wy1 = (iy0 + 1 >= 0 && iy0 + 1 < 64) ? wyf : 0.f;
        float wa  = (ix0 >= 0 && ix0 < 64) ? (1.f - wxf) : 0.f;
        float wbv = (ix0 + 1 >= 0 && ix0 + 1 < 64) ? wxf : 0.f;
        int base = i * 8;
        tab[base + 0] = (cy0 * 64 + px ) * 64;
        tab[base + 1] = (cy0 * 64 + px2) * 64;
        tab[base + 2] = (cy1 * 64 + px ) * 64;
        tab[base + 3] = (cy1 * 64 + px2) * 64;
        ((float*)tab)[base + 4] = wy0 * wa;   // w00
        ((float*)tab)[base + 5] = wy0 * wbv;  // w01
        ((float*)tab)[base + 6] = wy1 * wa;   // w10
        ((float*)tab)[base + 7] = wy1 * wbv;  // w11
    }
    if (t < 256) stat[t] = 0.f;
    __syncthreads();

    // ---- main tap loop ----
    // wave -> (oc-tile ot = wv&7, pixel-half ph = wv>>3); gathers 4 pixels w0p..w0p+3
    const int ot  = wv & 7;
    const int ph  = wv >> 3;
    const int w0p = wv * 4;
    f32x4 acc[2];
#pragma unroll
    for (int j = 0; j < 2; j++)
#pragma unroll
        for (int r = 0; r < 4; r++) acc[j][r] = 0.f;

    const unsigned short* wrow = wb + (ot * 16 + lo) * 1152 + quad * 8;

    // register-staged gather dwords for the CURRENT tap (statically indexed)
    unsigned u0[4], u1[4], u2[4], u3[4];
#pragma unroll
    for (int i = 0; i < 4; i++) {
        const int4 a = *(const int4*)&tab[(w0p + i) * 8];
        u0[i] = xtb[a.x + l]; u1[i] = xtb[a.y + l];
        u2[i] = xtb[a.z + l]; u3[i] = xtb[a.w + l];
    }

    for (int kt = 0; kt < KKT; kt++) {
        // EARLY A-frag issue: needed only after the barrier (~400 cy from here),
        // so the L2 latency is fully hidden. Single-buffered (16 VGPR).
        bf16x8 afc[4];
#pragma unroll
        for (int ch = 0; ch < 4; ch++)
            afc[ch] = *(const bf16x8*)(wrow + kt * 128 + ch * 32);

        unsigned* sb = (unsigned*)((kt & 1) ? samp1 : samp0);
        // bilinear from staged regs -> LDS (packed f32x2: even/odd channel)
#pragma unroll
        for (int i = 0; i < 4; i++) {
            const float4 tw = *(const float4*)&tab[(kt * 64 + w0p + i) * 8 + 4];
            f32x2 s = bf2(u0[i]) * tw.x;
            s += bf2(u1[i]) * tw.y;
            s += bf2(u2[i]) * tw.z;
            s += bf2(u3[i]) * tw.w;
            unsigned pk;
            asm("v_cvt_pk_bf16_f32 %0, %1, %2" : "=v"(pk) : "v"(s[0]), "v"(s[1]));
            int w = w0p + i;
            sb[w * 64 + ((g ^ (w & 15)) << 2) + (l & 3)] = pk;
        }
        // prefetch NEXT tap's gathers: stay in flight across barrier + MFMA
        if (kt < KKT - 1) {
#pragma unroll
            for (int i = 0; i < 4; i++) {
                const int4 a = *(const int4*)&tab[((kt + 1) * 64 + w0p + i) * 8];
                u0[i] = xtb[a.x + l]; u1[i] = xtb[a.y + l];
                u2[i] = xtb[a.z + l]; u3[i] = xtb[a.w + l];
            }
        }
        PUB_BARRIER();
        const unsigned short* sbs = (kt & 1) ? samp1 : samp0;
#pragma unroll
        for (int ch = 0; ch < 4; ch++) {
            int gg = ch * 4 + quad;
#pragma unroll
            for (int jj = 0; jj < 2; jj++) {
                int j = 2 * ph + jj;
                bf16x8 bfv = *(const bf16x8*)(sbs + (j * 16 + lo) * 128 + ((gg ^ lo) << 3));
                acc[jj] = __builtin_amdgcn_mfma_f32_16x16x32_bf16(afc[ch], bfv, acc[jj], 0, 0, 0);
            }
        }
    }

    // ---- epilogue: bias + store + fused BN stats ----
    float* ob = out + b * COUT * 4096 + h * 64;
#pragma unroll
    for (int r = 0; r < 4; r++) {
        int oc = ot * 16 + quad * 4 + r;
        float bia = b_def[oc];
        float ssum = 0.f, qsum = 0.f;
#pragma unroll
        for (int jj = 0; jj < 2; jj++) {
            int j = 2 * ph + jj;
            float v = acc[jj][r] + bia;
            ob[oc * 4096 + j * 16 + lo] = v;
            ssum += v; qsum += v * v;
        }
#pragma unroll
        for (int d = 1; d < 16; d <<= 1) {
            ssum += __shfl_xor(ssum, d, 64);
            qsum += __shfl_xor(qsum, d, 64);
        }
        if (lo == 0) { atomicAdd(&stat[oc], ssum); atomicAdd(&stat[128 + oc], qsum); }
    }
    __syncthreads();
    if (t < 256) {
        float* gp = (t < 128) ? (sums + t) : (sumsq + (t - 128));
        atomicAdd(gp, stat[t]);
    }
}

__global__ __launch_bounds__(256) void bn_silu_k(float* __restrict__ out,
                                                 const float* __restrict__ sums,
                                                 const float* __restrict__ sumsq,
                                                 const float* __restrict__ gamma,
                                                 const float* __restrict__ beta) {
    __shared__ float sc_s[128], sh_s[128];
    int t = threadIdx.x;
    if (t < 128) {
        const float invN = 1.f / NSTAT;
        float m = sums[t] * invN;
        float v = fmaf(-m, m, sumsq[t] * invN);
        float sc = gamma[t] * rsqrtf(v + 1e-5f);
        sc_s[t] = sc;
        sh_s[t] = beta[t] - m * sc;
    }
    __syncthreads();
    int i = blockIdx.x * 256 + t;
    float4 v = ((float4*)out)[i];
    int oc = (i >> 10) & 127;
    float sc = sc_s[oc], sh = sh_s[oc];
    float z0 = v.x * sc + sh;
    float z1 = v.y * sc + sh;
    float z2 = v.z * sc + sh;
    float z3 = v.w * sc + sh;
    v.x = z0 / (1.f + __expf(-z0));
    v.y = z1 / (1.f + __expf(-z1));
    v.z = z2 / (1.f + __expf(-z2));
    v.w = z3 / (1.f + __expf(-z3));
    ((float4*)out)[i] = v;
}

extern "C" void kernel_launch(void* const* d_in, const int* in_sizes, int n_in,
                              void* d_out, int out_size, void* d_ws, size_t ws_size,
                              hipStream_t stream) {
    const float* x     = (const float*)d_in[0];
    const float* w_off = (const float*)d_in[1];
    const float* w_def = (const float*)d_in[2];
    const float* b_def = (const float*)d_in[3];
    const float* gamma = (const float*)d_in[4];
    const float* beta  = (const float*)d_in[5];
    float* out = (float*)d_out;

    unsigned*       xt   = (unsigned*)d_ws;                               // 16777216 B
    unsigned short* wb   = (unsigned short*)((char*)d_ws + 16777216);     // 294912 B
    unsigned short* wob  = (unsigned short*)((char*)d_ws + 17072128);     // 73728 B
    float*          sums = (float*)((char*)d_ws + 17145856);              // 128
    float*          sumsq = sums + 128;

    prep_all_k<<<873, 512, 0, stream>>>(x, xt, w_def, w_off, wb, wob, sums);
    deform_main_k<<<512, 1024, 0, stream>>>(xt, wb, wob, b_def, out, sums, sumsq);
    bn_silu_k<<<4096, 256, 0, stream>>>(out, sums, sumsq, gamma, beta);
}